// Round 3
// baseline (184.673 us; speedup 1.0000x reference)
//
#include <hip/hip_runtime.h>

// Gated delta rule recurrence S_t = S_{t-1} @ A_t + B_t, outputs all S_t.
// T=128, B*H=64 chains, D=64. Multi-level chunked scan (runtime geometry):
//   K1  (fold): chunk summaries (PA,PB) over CH-step chunks        [64*NC blocks]
//   K2a (fold): group summaries (GA,GB) over GS=4 chunks           [64*NG blocks]
//   K2b (scan): sequential over NG groups -> states into `out`     [64 blocks]
//   K2c (scan): chunk-start states within group -> into `out`      [64*NG blocks]
//   K3  (scan): in-chunk recurrence -> remaining states into `out` [64*NC blocks]
// Chunk/group boundary states are stored directly in `out`, so K3 does only
// CH-1 steps. All matmuls use split-bf16 MFMA (hi/lo, 3 products) on the
// transposed recurrence S^T <- A^T S^T (+ B^T).

constexpr int kT = 128;
constexpr int kBH = 64;
constexpr int kD = 64;
constexpr int kTile = kD * kD;

typedef __attribute__((ext_vector_type(8))) short short8;
typedef __attribute__((ext_vector_type(4))) short short4v;
typedef __attribute__((ext_vector_type(4))) float f32x4;

__device__ __forceinline__ unsigned short f2bf(float f) {
  unsigned int u = __float_as_uint(f);
  u += 0x7FFFu + ((u >> 16) & 1u);
  return (unsigned short)(u >> 16);
}
__device__ __forceinline__ float bf2f(unsigned short h) {
  return __uint_as_float(((unsigned int)h) << 16);
}
// XOR swizzle (ushort units) for [64][64] bf16 planes: byte ^= (row&7)<<4.
__device__ __forceinline__ int swzi(int r, int c) { return (r * 64 + c) ^ ((r & 7) << 3); }

__device__ __forceinline__ f32x4 mfma16(short8 a, short8 b, f32x4 c) {
  return __builtin_amdgcn_mfma_f32_16x16x32_bf16(a, b, c, 0, 0, 0);
}

__device__ __forceinline__ void split4(const f32x4 v, short4v& h, short4v& l) {
#pragma unroll
  for (int i = 0; i < 4; ++i) {
    const unsigned short hh = f2bf(v[i]);
    h[i] = (short)hh;
    l[i] = (short)f2bf(v[i] - bf2f(hh));
  }
}

// ---------------- generic fold: (pa,pb) <- fold of nElem (A,B) elements ----------------
// element i tile index: e0 + i*elemStride, where e0 = bh*chainBase + id*idxBase,
// bh = blk/perChain, id = blk%perChain. dst tile index = blockIdx.x.
__global__ __launch_bounds__(256, 2) void gdr_fold(
    const float* __restrict__ srcA, const float* __restrict__ srcB,
    float* __restrict__ dstA, float* __restrict__ dstB,
    int perChain, long chainBase, long idxBase, long elemStride, int nElem) {
  __shared__ unsigned short sAh[4096], sAl[4096];
  __shared__ unsigned short sPAh[4096], sPAl[4096];
  __shared__ unsigned short sPBh[4096], sPBl[4096];

  const int tid = threadIdx.x;
  const int lane = tid & 63, wave = tid >> 6;
  const int wr = wave >> 1, wc = wave & 1;
  const int q = lane >> 4, l15 = lane & 15;
  const int bh = blockIdx.x / perChain, id = blockIdx.x % perChain;
  const long e0 = (long)bh * chainBase + (long)id * idxBase;
  const int an = lane, akb = wave;

  f32x4 apa[2][2], apb[2][2];
  {
    const float* At = srcA + (size_t)e0 * kTile;
    const float* Bt = srcB + (size_t)e0 * kTile;
#pragma unroll
    for (int mi = 0; mi < 2; ++mi)
#pragma unroll
      for (int ni = 0; ni < 2; ++ni) {
        const int off = (wc * 32 + ni * 16 + l15) * 64 + wr * 32 + mi * 16 + q * 4;
        apa[mi][ni] = *reinterpret_cast<const f32x4*>(At + off);
        apb[mi][ni] = *reinterpret_cast<const f32x4*>(Bt + off);
      }
  }

  float pfA[16];
  f32x4 pfB[2][2];
  {
    const float* At = srcA + (size_t)(e0 + elemStride) * kTile;
    const float* Bt = srcB + (size_t)(e0 + elemStride) * kTile;
#pragma unroll
    for (int kk = 0; kk < 16; ++kk) pfA[kk] = At[(akb * 16 + kk) * 64 + an];
#pragma unroll
    for (int mi = 0; mi < 2; ++mi)
#pragma unroll
      for (int ni = 0; ni < 2; ++ni)
        pfB[mi][ni] = *reinterpret_cast<const f32x4*>(
            Bt + (wc * 32 + ni * 16 + l15) * 64 + wr * 32 + mi * 16 + q * 4);
  }

  for (int i = 1; i < nElem; ++i) {
    if (i > 1) __syncthreads();
#pragma unroll
    for (int mi = 0; mi < 2; ++mi)
#pragma unroll
      for (int ni = 0; ni < 2; ++ni) {
        const int b = wc * 32 + ni * 16 + l15;
        const int a0 = wr * 32 + mi * 16 + q * 4;
        const int idx = swzi(b, a0);
        short4v h, l;
        split4(apa[mi][ni], h, l);
        *reinterpret_cast<short4v*>(&sPAh[idx]) = h;
        *reinterpret_cast<short4v*>(&sPAl[idx]) = l;
        split4(apb[mi][ni], h, l);
        *reinterpret_cast<short4v*>(&sPBh[idx]) = h;
        *reinterpret_cast<short4v*>(&sPBl[idx]) = l;
      }
#pragma unroll
    for (int s = 0; s < 2; ++s) {
      short8 h, l;
#pragma unroll
      for (int j = 0; j < 8; ++j) {
        const float v = pfA[s * 8 + j];
        const unsigned short hh = f2bf(v);
        h[j] = (short)hh;
        l[j] = (short)f2bf(v - bf2f(hh));
      }
      const int idx = swzi(an, akb * 16 + s * 8);
      *reinterpret_cast<short8*>(&sAh[idx]) = h;
      *reinterpret_cast<short8*>(&sAl[idx]) = l;
    }
    __syncthreads();

#pragma unroll
    for (int mi = 0; mi < 2; ++mi)
#pragma unroll
      for (int ni = 0; ni < 2; ++ni) {
        apa[mi][ni] = (f32x4){0.f, 0.f, 0.f, 0.f};
        apb[mi][ni] = pfB[mi][ni];
      }

    const int in = (i + 1 < nElem) ? i + 1 : i;
    {
      const float* At = srcA + (size_t)(e0 + (long)in * elemStride) * kTile;
      const float* Bt = srcB + (size_t)(e0 + (long)in * elemStride) * kTile;
#pragma unroll
      for (int kk = 0; kk < 16; ++kk) pfA[kk] = At[(akb * 16 + kk) * 64 + an];
#pragma unroll
      for (int mi = 0; mi < 2; ++mi)
#pragma unroll
        for (int ni = 0; ni < 2; ++ni)
          pfB[mi][ni] = *reinterpret_cast<const f32x4*>(
              Bt + (wc * 32 + ni * 16 + l15) * 64 + wr * 32 + mi * 16 + q * 4);
    }

#pragma unroll
    for (int ks = 0; ks < 2; ++ks) {
      short8 xh[2], xl[2], yah[2], yal[2], ybh[2], ybl[2];
      const int colb = ks * 32 + q * 8;
#pragma unroll
      for (int mi = 0; mi < 2; ++mi) {
        const int idx = swzi(wr * 32 + mi * 16 + l15, colb);
        xh[mi] = *reinterpret_cast<const short8*>(&sAh[idx]);
        xl[mi] = *reinterpret_cast<const short8*>(&sAl[idx]);
      }
#pragma unroll
      for (int ni = 0; ni < 2; ++ni) {
        const int idx = swzi(wc * 32 + ni * 16 + l15, colb);
        yah[ni] = *reinterpret_cast<const short8*>(&sPAh[idx]);
        yal[ni] = *reinterpret_cast<const short8*>(&sPAl[idx]);
        ybh[ni] = *reinterpret_cast<const short8*>(&sPBh[idx]);
        ybl[ni] = *reinterpret_cast<const short8*>(&sPBl[idx]);
      }
#pragma unroll
      for (int mi = 0; mi < 2; ++mi)
#pragma unroll
        for (int ni = 0; ni < 2; ++ni) {
          apa[mi][ni] = mfma16(xh[mi], yah[ni], apa[mi][ni]);
          apa[mi][ni] = mfma16(xh[mi], yal[ni], apa[mi][ni]);
          apa[mi][ni] = mfma16(xl[mi], yah[ni], apa[mi][ni]);
          apb[mi][ni] = mfma16(xh[mi], ybh[ni], apb[mi][ni]);
          apb[mi][ni] = mfma16(xh[mi], ybl[ni], apb[mi][ni]);
          apb[mi][ni] = mfma16(xl[mi], ybh[ni], apb[mi][ni]);
        }
    }
  }

  float* pao = dstA + (size_t)blockIdx.x * kTile;
  float* pbo = dstB + (size_t)blockIdx.x * kTile;
#pragma unroll
  for (int mi = 0; mi < 2; ++mi)
#pragma unroll
    for (int ni = 0; ni < 2; ++ni) {
      const int off = (wc * 32 + ni * 16 + l15) * 64 + wr * 32 + mi * 16 + q * 4;
      *reinterpret_cast<f32x4*>(pao + off) = apa[mi][ni];
      *reinterpret_cast<f32x4*>(pbo + off) = apb[mi][ni];
    }
}

// ---------------- generic scan: apply nSteps elements, write states into out ----------------
// start state: t = id*tbMul - 1 (<0 -> S0[bh]); step i writes out at
// t = id*tbMul + (i+1)*tStep - 1, tile index t*kBH + bh.
__global__ __launch_bounds__(256, 2) void gdr_scan(
    const float* __restrict__ srcA, const float* __restrict__ srcB,
    const float* __restrict__ S0, float* __restrict__ out,
    int perChain, long chainBase, long idxBase, long elemStride,
    int nSteps, int tbMul, int tStep) {
  __shared__ unsigned short sAh[4096], sAl[4096];
  __shared__ unsigned short sSh[4096], sSl[4096];

  const int tid = threadIdx.x;
  const int lane = tid & 63, wave = tid >> 6;
  const int wr = wave >> 1, wc = wave & 1;
  const int q = lane >> 4, l15 = lane & 15;
  const int bh = blockIdx.x / perChain, id = blockIdx.x % perChain;
  const long e0 = (long)bh * chainBase + (long)id * idxBase;
  const int tBase = id * tbMul;
  const int an = lane, akb = wave;

  f32x4 acc[2][2];
  {
    const float* Sb = (tBase == 0) ? (S0 + (size_t)bh * kTile)
                                   : (out + ((size_t)(tBase - 1) * kBH + bh) * kTile);
#pragma unroll
    for (int mi = 0; mi < 2; ++mi)
#pragma unroll
      for (int ni = 0; ni < 2; ++ni)
        acc[mi][ni] = *reinterpret_cast<const f32x4*>(
            Sb + (wc * 32 + ni * 16 + l15) * 64 + wr * 32 + mi * 16 + q * 4);
  }

  float pfA[16];
  f32x4 pfB[2][2];
  {
    const float* At = srcA + (size_t)e0 * kTile;
    const float* Bt = srcB + (size_t)e0 * kTile;
#pragma unroll
    for (int kk = 0; kk < 16; ++kk) pfA[kk] = At[(akb * 16 + kk) * 64 + an];
#pragma unroll
    for (int mi = 0; mi < 2; ++mi)
#pragma unroll
      for (int ni = 0; ni < 2; ++ni)
        pfB[mi][ni] = *reinterpret_cast<const f32x4*>(
            Bt + (wc * 32 + ni * 16 + l15) * 64 + wr * 32 + mi * 16 + q * 4);
  }

  for (int i = 0; i < nSteps; ++i) {
    if (i) __syncthreads();
#pragma unroll
    for (int mi = 0; mi < 2; ++mi)
#pragma unroll
      for (int ni = 0; ni < 2; ++ni) {
        const int b = wc * 32 + ni * 16 + l15;
        const int a0 = wr * 32 + mi * 16 + q * 4;
        const int idx = swzi(b, a0);
        short4v h, l;
        split4(acc[mi][ni], h, l);
        *reinterpret_cast<short4v*>(&sSh[idx]) = h;
        *reinterpret_cast<short4v*>(&sSl[idx]) = l;
      }
#pragma unroll
    for (int s = 0; s < 2; ++s) {
      short8 h, l;
#pragma unroll
      for (int j = 0; j < 8; ++j) {
        const float v = pfA[s * 8 + j];
        const unsigned short hh = f2bf(v);
        h[j] = (short)hh;
        l[j] = (short)f2bf(v - bf2f(hh));
      }
      const int idx = swzi(an, akb * 16 + s * 8);
      *reinterpret_cast<short8*>(&sAh[idx]) = h;
      *reinterpret_cast<short8*>(&sAl[idx]) = l;
    }
    __syncthreads();

#pragma unroll
    for (int mi = 0; mi < 2; ++mi)
#pragma unroll
      for (int ni = 0; ni < 2; ++ni)
        acc[mi][ni] = pfB[mi][ni];

    const int in = (i + 1 < nSteps) ? i + 1 : i;
    {
      const float* At = srcA + (size_t)(e0 + (long)in * elemStride) * kTile;
      const float* Bt = srcB + (size_t)(e0 + (long)in * elemStride) * kTile;
#pragma unroll
      for (int kk = 0; kk < 16; ++kk) pfA[kk] = At[(akb * 16 + kk) * 64 + an];
#pragma unroll
      for (int mi = 0; mi < 2; ++mi)
#pragma unroll
        for (int ni = 0; ni < 2; ++ni)
          pfB[mi][ni] = *reinterpret_cast<const f32x4*>(
              Bt + (wc * 32 + ni * 16 + l15) * 64 + wr * 32 + mi * 16 + q * 4);
    }

#pragma unroll
    for (int ks = 0; ks < 2; ++ks) {
      short8 xh[2], xl[2], yh[2], yl[2];
      const int colb = ks * 32 + q * 8;
#pragma unroll
      for (int mi = 0; mi < 2; ++mi) {
        const int idx = swzi(wr * 32 + mi * 16 + l15, colb);
        xh[mi] = *reinterpret_cast<const short8*>(&sAh[idx]);
        xl[mi] = *reinterpret_cast<const short8*>(&sAl[idx]);
      }
#pragma unroll
      for (int ni = 0; ni < 2; ++ni) {
        const int idx = swzi(wc * 32 + ni * 16 + l15, colb);
        yh[ni] = *reinterpret_cast<const short8*>(&sSh[idx]);
        yl[ni] = *reinterpret_cast<const short8*>(&sSl[idx]);
      }
#pragma unroll
      for (int mi = 0; mi < 2; ++mi)
#pragma unroll
        for (int ni = 0; ni < 2; ++ni) {
          acc[mi][ni] = mfma16(xh[mi], yh[ni], acc[mi][ni]);
          acc[mi][ni] = mfma16(xh[mi], yl[ni], acc[mi][ni]);
          acc[mi][ni] = mfma16(xl[mi], yh[ni], acc[mi][ni]);
        }
    }

    const int t = tBase + (i + 1) * tStep - 1;
    float* o = out + ((size_t)t * kBH + bh) * kTile;
#pragma unroll
    for (int mi = 0; mi < 2; ++mi)
#pragma unroll
      for (int ni = 0; ni < 2; ++ni) {
        const int off = (wc * 32 + ni * 16 + l15) * 64 + wr * 32 + mi * 16 + q * 4;
        *reinterpret_cast<f32x4*>(o + off) = acc[mi][ni];
      }
  }
}

extern "C" void kernel_launch(void* const* d_in, const int* in_sizes, int n_in,
                              void* d_out, int out_size, void* d_ws, size_t ws_size,
                              hipStream_t stream) {
  const float* A  = (const float*)d_in[0];
  const float* Bm = (const float*)d_in[1];
  const float* S0 = (const float*)d_in[2];
  float* out = (float*)d_out;

  // geometry: NC chunks of CH steps; NG = NC/4 groups of 4 chunks.
  // ws: PA[64*NC], PB[64*NC], GA[64*NG], GB[64*NG] tiles of 16 KB.
  int NC;
  if (ws_size >= (size_t)5120 * kTile * 4)      NC = 32;  // 80 MB
  else if (ws_size >= (size_t)2560 * kTile * 4) NC = 16;  // 40 MB
  else                                          NC = 8;   // 20 MB
  const int CH = kT / NC;
  const int NG = NC / 4;

  float* PA = (float*)d_ws;
  float* PB = PA + (size_t)kBH * NC * kTile;
  float* GA = PB + (size_t)kBH * NC * kTile;
  float* GB = GA + (size_t)kBH * NG * kTile;

  // K1: chunk summaries. elem idx = (ck*CH + i)*kBH + bh
  gdr_fold<<<dim3(kBH * NC), dim3(256), 0, stream>>>(
      A, Bm, PA, PB, NC, 1L, (long)CH * kBH, (long)kBH, CH);
  // K2a: group summaries. elem idx = bh*NC + g*4 + i
  gdr_fold<<<dim3(kBH * NG), dim3(256), 0, stream>>>(
      PA, PB, GA, GB, NG, (long)NC, 4L, 1L, 4);
  // K2b: scan NG groups; writes out at t = (i+1)*4*CH - 1
  gdr_scan<<<dim3(kBH), dim3(256), 0, stream>>>(
      GA, GB, S0, out, 1, (long)NG, 0L, 1L, NG, 0, 4 * CH);
  // K2c: chunk starts within group; elem idx = bh*NC + g*4 + i,
  //      start t = g*4*CH - 1, writes t = g*4*CH + (i+1)*CH - 1
  gdr_scan<<<dim3(kBH * NG), dim3(256), 0, stream>>>(
      PA, PB, S0, out, NG, (long)NC, 4L, 1L, 3, 4 * CH, CH);
  // K3: in-chunk recurrence; elem idx = (ck*CH + i)*kBH + bh,
  //     start t = ck*CH - 1, writes t = ck*CH + i  (i = 0..CH-2)
  gdr_scan<<<dim3(kBH * NC), dim3(256), 0, stream>>>(
      A, Bm, S0, out, NC, 1L, (long)CH * kBH, (long)kBH, CH - 1, CH, 1);
}

// Round 4
// 159.245 us; speedup vs baseline: 1.1597x; 1.1597x over previous
//
#include <hip/hip_runtime.h>

// Gated delta rule recurrence S_t = S_{t-1} @ A_t + B_t, outputs all S_t.
// T=128, B*H=64 chains, D=64. Two-level chunked scan, NC=16 chunks of CH=8.
//   K1 (fold): chunk summaries (PA,PB)           [1024 blocks x 7 steps]
//   K2 (scan): over 16 summaries -> chunk-end states into out [64 blocks]
//   K3 (scan): in-chunk recurrence -> remaining states        [1024 blocks]
// Split-bf16 MFMA (hi/lo, 3 products). KEY CHANGE vs r2/r3: accumulator
// never touches LDS. Each wave owns a 16-ROW strip of S; the C/D->B-operand
// transform is a 4-lane in-register regroup via ds_bpermute (rows tied to
// lane&15 in both layouts). Only A is LDS-staged (double-buffered), so each
// step has ONE barrier and the barrier never waits on MFMA results.

constexpr int kT = 128;
constexpr int kBH = 64;
constexpr int kD = 64;
constexpr int kTile = kD * kD;
constexpr int kNC = 16;
constexpr int kCH = 8;

typedef __attribute__((ext_vector_type(8))) short short8;
typedef __attribute__((ext_vector_type(4))) float f32x4;
using u32 = unsigned int;

union U8 { u32 u[4]; short8 s; };

// XOR swizzle (ushort units) for [64][64] bf16 planes: byte ^= (row&7)<<4.
__device__ __forceinline__ int swzi(int r, int c) { return (r * 64 + c) ^ ((r & 7) << 3); }

__device__ __forceinline__ f32x4 mfma16(short8 a, short8 b, f32x4 c) {
  return __builtin_amdgcn_mfma_f32_16x16x32_bf16(a, b, c, 0, 0, 0);
}

// split 2 floats into packed hi/lo bf16 pairs (1 v_cvt_pk each + exact residual)
__device__ __forceinline__ void pk_split(float a, float b, u32& h, u32& l) {
  u32 hu;
  asm("v_cvt_pk_bf16_f32 %0, %1, %2" : "=v"(hu) : "v"(a), "v"(b));
  const float ra = a - __uint_as_float(hu << 16);
  const float rb = b - __uint_as_float(hu & 0xffff0000u);
  u32 lu;
  asm("v_cvt_pk_bf16_f32 %0, %1, %2" : "=v"(lu) : "v"(ra), "v"(rb));
  h = hu;
  l = lu;
}

// Build one K=32 B-operand fragment from two C/D tiles (X = tile 2ks, Y = 2ks+1),
// one plane (hi or lo). p01/p23 = packed (i0,i1)/(i2,i3) of X; q* of Y.
// Dest lane l (q=l>>4, n=l&15): j-pair cols ks*32+q*8+{0..7} <- pulls verified:
// v0: [X@q0, X@q2, Y@q0, Y@q2], v2: [X@q1, X@q3, Y@q1, Y@q3] (same +16 addr).
__device__ __forceinline__ short8 gather_frag(u32 p01, u32 p23, u32 q01, u32 q23,
                                              int ad0, int ad1, bool lowh) {
  U8 r;
  int x, y;
  x = __builtin_amdgcn_ds_bpermute(ad0, (int)p01);
  y = __builtin_amdgcn_ds_bpermute(ad0, (int)q01);
  r.u[0] = (u32)(lowh ? x : y);
  x = __builtin_amdgcn_ds_bpermute(ad0, (int)p23);
  y = __builtin_amdgcn_ds_bpermute(ad0, (int)q23);
  r.u[1] = (u32)(lowh ? x : y);
  x = __builtin_amdgcn_ds_bpermute(ad1, (int)p01);
  y = __builtin_amdgcn_ds_bpermute(ad1, (int)q01);
  r.u[2] = (u32)(lowh ? x : y);
  x = __builtin_amdgcn_ds_bpermute(ad1, (int)p23);
  y = __builtin_amdgcn_ds_bpermute(ad1, (int)q23);
  r.u[3] = (u32)(lowh ? x : y);
  return r.s;
}

__device__ __forceinline__ void load_pfA(float* pfA, const float* At, int lane, int w) {
#pragma unroll
  for (int kk = 0; kk < 16; ++kk) pfA[kk] = At[(w * 16 + kk) * 64 + lane];
}
__device__ __forceinline__ void load_pfB(f32x4* pfB, const float* Bt, int rowbase, int q) {
#pragma unroll
  for (int cm = 0; cm < 4; ++cm)
    pfB[cm] = *reinterpret_cast<const f32x4*>(Bt + rowbase + cm * 16 + q * 4);
}

// stage A^T into LDS plane pair: thread (w,lane) writes sA[row=lane][cols w*16..+15]
__device__ __forceinline__ void stage_A(unsigned short* Ah, unsigned short* Al,
                                        const float* pfA, int lane, int w) {
#pragma unroll
  for (int s = 0; s < 2; ++s) {
    U8 h, l;
#pragma unroll
    for (int p = 0; p < 4; ++p) {
      u32 hu, lu;
      pk_split(pfA[s * 8 + 2 * p], pfA[s * 8 + 2 * p + 1], hu, lu);
      h.u[p] = hu;
      l.u[p] = lu;
    }
    const int idx = swzi(lane, w * 16 + s * 8);
    *reinterpret_cast<short8*>(&Ah[idx]) = h.s;
    *reinterpret_cast<short8*>(&Al[idx]) = l.s;
  }
}

// ---------------- fold: (pa,pb) <- fold of nElem (A,B) elements ----------------
__global__ __launch_bounds__(256, 3) void gdr_fold(
    const float* __restrict__ srcA, const float* __restrict__ srcB,
    float* __restrict__ dstA, float* __restrict__ dstB,
    int perChain, long chainBase, long idxBase, long elemStride, int nElem) {
  __shared__ unsigned short sAh[2][4096], sAl[2][4096];

  const int tid = threadIdx.x;
  const int lane = tid & 63, w = tid >> 6;
  const int q = lane >> 4, l15 = lane & 15;
  const int bh = blockIdx.x / perChain, id = blockIdx.x % perChain;
  const long e0 = (long)bh * chainBase + (long)id * idxBase;
  const int rowbase = (w * 16 + l15) * 64;
  const int ad0 = (l15 + ((lane >> 4) & 1) * 32) * 4;
  const int ad1 = ad0 + 64;
  const bool lowh = lane < 32;
  const int nS = nElem - 1;  // steps applying elements 1..nElem-1

  f32x4 apa[4], apb[4];
  {
    const float* At = srcA + (size_t)e0 * kTile;
    const float* Bt = srcB + (size_t)e0 * kTile;
#pragma unroll
    for (int cm = 0; cm < 4; ++cm) {
      apa[cm] = *reinterpret_cast<const f32x4*>(At + rowbase + cm * 16 + q * 4);
      apb[cm] = *reinterpret_cast<const f32x4*>(Bt + rowbase + cm * 16 + q * 4);
    }
  }

  float pfA[16];
  f32x4 pfB[4];
  load_pfA(pfA, srcA + (size_t)(e0 + elemStride) * kTile, lane, w);
  stage_A(sAh[0], sAl[0], pfA, lane, w);
  __syncthreads();
  {
    const long e2 = e0 + (long)(nS > 1 ? 2 : 1) * elemStride;
    load_pfA(pfA, srcA + (size_t)e2 * kTile, lane, w);
    load_pfB(pfB, srcB + (size_t)(e0 + elemStride) * kTile, rowbase, q);
  }

  for (int j = 0; j < nS; ++j) {
    const int cur = j & 1;
    f32x4 npa[4], npb[4];
#pragma unroll
    for (int cm = 0; cm < 4; ++cm) {
      npa[cm] = (f32x4){0.f, 0.f, 0.f, 0.f};
      npb[cm] = pfB[cm];
    }
#pragma unroll
    for (int ks = 0; ks < 2; ++ks) {
      u32 pa01h, pa01l, pa23h, pa23l, qa01h, qa01l, qa23h, qa23l;
      u32 pb01h, pb01l, pb23h, pb23l, qb01h, qb01l, qb23h, qb23l;
      pk_split(apa[2 * ks][0], apa[2 * ks][1], pa01h, pa01l);
      pk_split(apa[2 * ks][2], apa[2 * ks][3], pa23h, pa23l);
      pk_split(apa[2 * ks + 1][0], apa[2 * ks + 1][1], qa01h, qa01l);
      pk_split(apa[2 * ks + 1][2], apa[2 * ks + 1][3], qa23h, qa23l);
      pk_split(apb[2 * ks][0], apb[2 * ks][1], pb01h, pb01l);
      pk_split(apb[2 * ks][2], apb[2 * ks][3], pb23h, pb23l);
      pk_split(apb[2 * ks + 1][0], apb[2 * ks + 1][1], qb01h, qb01l);
      pk_split(apb[2 * ks + 1][2], apb[2 * ks + 1][3], qb23h, qb23l);
      const short8 bah = gather_frag(pa01h, pa23h, qa01h, qa23h, ad0, ad1, lowh);
      const short8 bal = gather_frag(pa01l, pa23l, qa01l, qa23l, ad0, ad1, lowh);
      const short8 bbh = gather_frag(pb01h, pb23h, qb01h, qb23h, ad0, ad1, lowh);
      const short8 bbl = gather_frag(pb01l, pb23l, qb01l, qb23l, ad0, ad1, lowh);
#pragma unroll
      for (int cm = 0; cm < 4; ++cm) {
        const int ai = swzi(cm * 16 + l15, ks * 32 + q * 8);
        const short8 ah = *reinterpret_cast<const short8*>(&sAh[cur][ai]);
        const short8 al = *reinterpret_cast<const short8*>(&sAl[cur][ai]);
        npa[cm] = mfma16(ah, bah, npa[cm]);
        npa[cm] = mfma16(ah, bal, npa[cm]);
        npa[cm] = mfma16(al, bah, npa[cm]);
        npb[cm] = mfma16(ah, bbh, npb[cm]);
        npb[cm] = mfma16(ah, bbl, npb[cm]);
        npb[cm] = mfma16(al, bbh, npb[cm]);
      }
    }
    if (j + 1 < nS) {
      stage_A(sAh[cur ^ 1], sAl[cur ^ 1], pfA, lane, w);  // element j+2
      const int ja = (j + 3 <= nS) ? j + 3 : nS;          // element j+3 clamped
      load_pfA(pfA, srcA + (size_t)(e0 + (long)ja * elemStride) * kTile, lane, w);
      load_pfB(pfB, srcB + (size_t)(e0 + (long)(j + 2) * elemStride) * kTile, rowbase, q);
    }
#pragma unroll
    for (int cm = 0; cm < 4; ++cm) { apa[cm] = npa[cm]; apb[cm] = npb[cm]; }
    if (j + 1 < nS) __syncthreads();
  }

  float* pao = dstA + (size_t)blockIdx.x * kTile;
  float* pbo = dstB + (size_t)blockIdx.x * kTile;
#pragma unroll
  for (int cm = 0; cm < 4; ++cm) {
    *reinterpret_cast<f32x4*>(pao + rowbase + cm * 16 + q * 4) = apa[cm];
    *reinterpret_cast<f32x4*>(pbo + rowbase + cm * 16 + q * 4) = apb[cm];
  }
}

// ---------------- scan: apply nSteps elements, write states into out ----------------
__global__ __launch_bounds__(256, 4) void gdr_scan(
    const float* __restrict__ srcA, const float* __restrict__ srcB,
    const float* __restrict__ S0, float* __restrict__ out,
    int perChain, long chainBase, long idxBase, long elemStride,
    int nSteps, int tbMul, int tStep) {
  __shared__ unsigned short sAh[2][4096], sAl[2][4096];

  const int tid = threadIdx.x;
  const int lane = tid & 63, w = tid >> 6;
  const int q = lane >> 4, l15 = lane & 15;
  const int bh = blockIdx.x / perChain, id = blockIdx.x % perChain;
  const long e0 = (long)bh * chainBase + (long)id * idxBase;
  const int tBase = id * tbMul;
  const int rowbase = (w * 16 + l15) * 64;
  const int ad0 = (l15 + ((lane >> 4) & 1) * 32) * 4;
  const int ad1 = ad0 + 64;
  const bool lowh = lane < 32;

  f32x4 acc[4];
  {
    const float* Sb = (tBase == 0) ? (S0 + (size_t)bh * kTile)
                                   : (out + ((size_t)(tBase - 1) * kBH + bh) * kTile);
#pragma unroll
    for (int cm = 0; cm < 4; ++cm)
      acc[cm] = *reinterpret_cast<const f32x4*>(Sb + rowbase + cm * 16 + q * 4);
  }

  float pfA[16];
  f32x4 pfB[4];
  load_pfA(pfA, srcA + (size_t)e0 * kTile, lane, w);
  stage_A(sAh[0], sAl[0], pfA, lane, w);
  __syncthreads();
  {
    const long e1 = e0 + (long)(nSteps > 1 ? 1 : 0) * elemStride;
    load_pfA(pfA, srcA + (size_t)e1 * kTile, lane, w);
    load_pfB(pfB, srcB + (size_t)e0 * kTile, rowbase, q);
  }

  for (int i = 0; i < nSteps; ++i) {
    const int cur = i & 1;
    f32x4 nacc[4];
#pragma unroll
    for (int cm = 0; cm < 4; ++cm) nacc[cm] = pfB[cm];
#pragma unroll
    for (int ks = 0; ks < 2; ++ks) {
      u32 p01h, p01l, p23h, p23l, q01h, q01l, q23h, q23l;
      pk_split(acc[2 * ks][0], acc[2 * ks][1], p01h, p01l);
      pk_split(acc[2 * ks][2], acc[2 * ks][3], p23h, p23l);
      pk_split(acc[2 * ks + 1][0], acc[2 * ks + 1][1], q01h, q01l);
      pk_split(acc[2 * ks + 1][2], acc[2 * ks + 1][3], q23h, q23l);
      const short8 bfh = gather_frag(p01h, p23h, q01h, q23h, ad0, ad1, lowh);
      const short8 bfl = gather_frag(p01l, p23l, q01l, q23l, ad0, ad1, lowh);
#pragma unroll
      for (int cm = 0; cm < 4; ++cm) {
        const int ai = swzi(cm * 16 + l15, ks * 32 + q * 8);
        const short8 ah = *reinterpret_cast<const short8*>(&sAh[cur][ai]);
        const short8 al = *reinterpret_cast<const short8*>(&sAl[cur][ai]);
        nacc[cm] = mfma16(ah, bfh, nacc[cm]);
        nacc[cm] = mfma16(ah, bfl, nacc[cm]);
        nacc[cm] = mfma16(al, bfh, nacc[cm]);
      }
    }
    if (i + 1 < nSteps) {
      stage_A(sAh[cur ^ 1], sAl[cur ^ 1], pfA, lane, w);  // element i+1
      const int ia = (i + 2 <= nSteps - 1) ? i + 2 : nSteps - 1;
      load_pfA(pfA, srcA + (size_t)(e0 + (long)ia * elemStride) * kTile, lane, w);
      load_pfB(pfB, srcB + (size_t)(e0 + (long)(i + 1) * elemStride) * kTile, rowbase, q);
    }
    // write state t
    const int t = tBase + (i + 1) * tStep - 1;
    float* o = out + ((size_t)t * kBH + bh) * kTile;
#pragma unroll
    for (int cm = 0; cm < 4; ++cm) {
      *reinterpret_cast<f32x4*>(o + rowbase + cm * 16 + q * 4) = nacc[cm];
      acc[cm] = nacc[cm];
    }
    if (i + 1 < nSteps) __syncthreads();
  }
}

extern "C" void kernel_launch(void* const* d_in, const int* in_sizes, int n_in,
                              void* d_out, int out_size, void* d_ws, size_t ws_size,
                              hipStream_t stream) {
  const float* A  = (const float*)d_in[0];
  const float* Bm = (const float*)d_in[1];
  const float* S0 = (const float*)d_in[2];
  float* out = (float*)d_out;

  // workspace: PA[64*16], PB[64*16] tiles of 16 KB = 32 MB
  float* PA = (float*)d_ws;
  float* PB = PA + (size_t)kBH * kNC * kTile;

  // K1: chunk summaries. elements (ck*8+i)*64+bh, i=0..7
  gdr_fold<<<dim3(kBH * kNC), dim3(256), 0, stream>>>(
      A, Bm, PA, PB, kNC, 1L, (long)kCH * kBH, (long)kBH, kCH);
  // K2: scan 16 summaries (tiles bh*16+i); writes t = (i+1)*8-1 (7,15,...,127)
  gdr_scan<<<dim3(kBH), dim3(256), 0, stream>>>(
      PA, PB, S0, out, 1, (long)kNC, 0L, 1L, kNC, 0, kCH);
  // K3: in-chunk recurrence; elements (ck*8+i)*64+bh, start out[ck*8-1]/S0,
  //     writes t = ck*8+i for i=0..6
  gdr_scan<<<dim3(kBH * kNC), dim3(256), 0, stream>>>(
      A, Bm, S0, out, kNC, 1L, (long)kCH * kBH, (long)kBH, kCH - 1, kCH, 1);
}

// Round 5
// 152.853 us; speedup vs baseline: 1.2082x; 1.0418x over previous
//
#include <hip/hip_runtime.h>

// Gated delta rule recurrence S_t = S_{t-1} @ A_t + B_t, outputs all S_t.
// T=128, B*H=64 chains, D=64. Two-level chunked scan, NC=16 chunks of CH=8.
//   K1 (fold): chunk summaries (PA,PB)           [1024 blocks x 7 steps]
//   K2 (scan): over 16 summaries -> chunk-end states into out [64 blocks]
//   K3 (scan): in-chunk recurrence -> remaining states        [1024 blocks]
// Split-bf16 MFMA (hi/lo, 3 products). Accumulator lives in registers; the
// C/D->B-operand transform is a 4-lane in-register regroup via ds_bpermute.
// Only A is LDS-staged (double-buffered).
// r5 CHANGE: __syncthreads() (which drains vmcnt(0), serializing a full HBM
// round-trip into every step) is replaced by s_waitcnt lgkmcnt(0) + raw
// s_barrier, so global prefetches stay in flight across the barrier.
// Also __launch_bounds__(256,4): grid 1024 = exactly 4 blocks/CU, no tail.

constexpr int kT = 128;
constexpr int kBH = 64;
constexpr int kD = 64;
constexpr int kTile = kD * kD;
constexpr int kNC = 16;
constexpr int kCH = 8;

typedef __attribute__((ext_vector_type(8))) short short8;
typedef __attribute__((ext_vector_type(4))) float f32x4;
using u32 = unsigned int;

union U8 { u32 u[4]; short8 s; };

// Barrier that does NOT drain outstanding global loads: only LDS ops must
// complete (stage_A ds_writes for cross-wave visibility; this wave's ds_reads
// are drained too, so its MFMA operands are already in registers -> the
// double-buffer WAR is safe with a single barrier).
__device__ __forceinline__ void softBarrier() {
  asm volatile("s_waitcnt lgkmcnt(0)" ::: "memory");
  __builtin_amdgcn_s_barrier();
}

// XOR swizzle (ushort units) for [64][64] bf16 planes: byte ^= (row&7)<<4.
__device__ __forceinline__ int swzi(int r, int c) { return (r * 64 + c) ^ ((r & 7) << 3); }

__device__ __forceinline__ f32x4 mfma16(short8 a, short8 b, f32x4 c) {
  return __builtin_amdgcn_mfma_f32_16x16x32_bf16(a, b, c, 0, 0, 0);
}

// split 2 floats into packed hi/lo bf16 pairs (1 v_cvt_pk each + exact residual)
__device__ __forceinline__ void pk_split(float a, float b, u32& h, u32& l) {
  u32 hu;
  asm("v_cvt_pk_bf16_f32 %0, %1, %2" : "=v"(hu) : "v"(a), "v"(b));
  const float ra = a - __uint_as_float(hu << 16);
  const float rb = b - __uint_as_float(hu & 0xffff0000u);
  u32 lu;
  asm("v_cvt_pk_bf16_f32 %0, %1, %2" : "=v"(lu) : "v"(ra), "v"(rb));
  h = hu;
  l = lu;
}

// Build one K=32 B-operand fragment from two C/D tiles (X = tile 2ks, Y = 2ks+1),
// one plane (hi or lo).
__device__ __forceinline__ short8 gather_frag(u32 p01, u32 p23, u32 q01, u32 q23,
                                              int ad0, int ad1, bool lowh) {
  U8 r;
  int x, y;
  x = __builtin_amdgcn_ds_bpermute(ad0, (int)p01);
  y = __builtin_amdgcn_ds_bpermute(ad0, (int)q01);
  r.u[0] = (u32)(lowh ? x : y);
  x = __builtin_amdgcn_ds_bpermute(ad0, (int)p23);
  y = __builtin_amdgcn_ds_bpermute(ad0, (int)q23);
  r.u[1] = (u32)(lowh ? x : y);
  x = __builtin_amdgcn_ds_bpermute(ad1, (int)p01);
  y = __builtin_amdgcn_ds_bpermute(ad1, (int)q01);
  r.u[2] = (u32)(lowh ? x : y);
  x = __builtin_amdgcn_ds_bpermute(ad1, (int)p23);
  y = __builtin_amdgcn_ds_bpermute(ad1, (int)q23);
  r.u[3] = (u32)(lowh ? x : y);
  return r.s;
}

__device__ __forceinline__ void load_pfA(float* pfA, const float* At, int lane, int w) {
#pragma unroll
  for (int kk = 0; kk < 16; ++kk) pfA[kk] = At[(w * 16 + kk) * 64 + lane];
}
__device__ __forceinline__ void load_pfB(f32x4* pfB, const float* Bt, int rowbase, int q) {
#pragma unroll
  for (int cm = 0; cm < 4; ++cm)
    pfB[cm] = *reinterpret_cast<const f32x4*>(Bt + rowbase + cm * 16 + q * 4);
}

// stage A^T into LDS plane pair: thread (w,lane) writes sA[row=lane][cols w*16..+15]
__device__ __forceinline__ void stage_A(unsigned short* Ah, unsigned short* Al,
                                        const float* pfA, int lane, int w) {
#pragma unroll
  for (int s = 0; s < 2; ++s) {
    U8 h, l;
#pragma unroll
    for (int p = 0; p < 4; ++p) {
      u32 hu, lu;
      pk_split(pfA[s * 8 + 2 * p], pfA[s * 8 + 2 * p + 1], hu, lu);
      h.u[p] = hu;
      l.u[p] = lu;
    }
    const int idx = swzi(lane, w * 16 + s * 8);
    *reinterpret_cast<short8*>(&Ah[idx]) = h.s;
    *reinterpret_cast<short8*>(&Al[idx]) = l.s;
  }
}

// ---------------- fold: (pa,pb) <- fold of nElem (A,B) elements ----------------
__global__ __launch_bounds__(256, 4) void gdr_fold(
    const float* __restrict__ srcA, const float* __restrict__ srcB,
    float* __restrict__ dstA, float* __restrict__ dstB,
    int perChain, long chainBase, long idxBase, long elemStride, int nElem) {
  __shared__ unsigned short sAh[2][4096], sAl[2][4096];

  const int tid = threadIdx.x;
  const int lane = tid & 63, w = tid >> 6;
  const int q = lane >> 4, l15 = lane & 15;
  const int bh = blockIdx.x / perChain, id = blockIdx.x % perChain;
  const long e0 = (long)bh * chainBase + (long)id * idxBase;
  const int rowbase = (w * 16 + l15) * 64;
  const int ad0 = (l15 + ((lane >> 4) & 1) * 32) * 4;
  const int ad1 = ad0 + 64;
  const bool lowh = lane < 32;
  const int nS = nElem - 1;  // steps applying elements 1..nElem-1

  f32x4 apa[4], apb[4];
  {
    const float* At = srcA + (size_t)e0 * kTile;
    const float* Bt = srcB + (size_t)e0 * kTile;
#pragma unroll
    for (int cm = 0; cm < 4; ++cm) {
      apa[cm] = *reinterpret_cast<const f32x4*>(At + rowbase + cm * 16 + q * 4);
      apb[cm] = *reinterpret_cast<const f32x4*>(Bt + rowbase + cm * 16 + q * 4);
    }
  }

  float pfA[16];
  f32x4 pfB[4];
  load_pfA(pfA, srcA + (size_t)(e0 + elemStride) * kTile, lane, w);
  stage_A(sAh[0], sAl[0], pfA, lane, w);
  softBarrier();
  {
    const long e2 = e0 + (long)(nS > 1 ? 2 : 1) * elemStride;
    load_pfA(pfA, srcA + (size_t)e2 * kTile, lane, w);
    load_pfB(pfB, srcB + (size_t)(e0 + elemStride) * kTile, rowbase, q);
  }

  for (int j = 0; j < nS; ++j) {
    const int cur = j & 1;
    f32x4 npa[4], npb[4];
#pragma unroll
    for (int cm = 0; cm < 4; ++cm) {
      npa[cm] = (f32x4){0.f, 0.f, 0.f, 0.f};
      npb[cm] = pfB[cm];
    }
#pragma unroll
    for (int ks = 0; ks < 2; ++ks) {
      u32 pa01h, pa01l, pa23h, pa23l, qa01h, qa01l, qa23h, qa23l;
      u32 pb01h, pb01l, pb23h, pb23l, qb01h, qb01l, qb23h, qb23l;
      pk_split(apa[2 * ks][0], apa[2 * ks][1], pa01h, pa01l);
      pk_split(apa[2 * ks][2], apa[2 * ks][3], pa23h, pa23l);
      pk_split(apa[2 * ks + 1][0], apa[2 * ks + 1][1], qa01h, qa01l);
      pk_split(apa[2 * ks + 1][2], apa[2 * ks + 1][3], qa23h, qa23l);
      pk_split(apb[2 * ks][0], apb[2 * ks][1], pb01h, pb01l);
      pk_split(apb[2 * ks][2], apb[2 * ks][3], pb23h, pb23l);
      pk_split(apb[2 * ks + 1][0], apb[2 * ks + 1][1], qb01h, qb01l);
      pk_split(apb[2 * ks + 1][2], apb[2 * ks + 1][3], qb23h, qb23l);
      const short8 bah = gather_frag(pa01h, pa23h, qa01h, qa23h, ad0, ad1, lowh);
      const short8 bal = gather_frag(pa01l, pa23l, qa01l, qa23l, ad0, ad1, lowh);
      const short8 bbh = gather_frag(pb01h, pb23h, qb01h, qb23h, ad0, ad1, lowh);
      const short8 bbl = gather_frag(pb01l, pb23l, qb01l, qb23l, ad0, ad1, lowh);
#pragma unroll
      for (int cm = 0; cm < 4; ++cm) {
        const int ai = swzi(cm * 16 + l15, ks * 32 + q * 8);
        const short8 ah = *reinterpret_cast<const short8*>(&sAh[cur][ai]);
        const short8 al = *reinterpret_cast<const short8*>(&sAl[cur][ai]);
        npa[cm] = mfma16(ah, bah, npa[cm]);
        npa[cm] = mfma16(ah, bal, npa[cm]);
        npa[cm] = mfma16(al, bah, npa[cm]);
        npb[cm] = mfma16(ah, bbh, npb[cm]);
        npb[cm] = mfma16(ah, bbl, npb[cm]);
        npb[cm] = mfma16(al, bbh, npb[cm]);
      }
    }
    if (j + 1 < nS) {
      stage_A(sAh[cur ^ 1], sAl[cur ^ 1], pfA, lane, w);  // element j+2
      const int ja = (j + 3 <= nS) ? j + 3 : nS;          // element j+3 clamped
      load_pfA(pfA, srcA + (size_t)(e0 + (long)ja * elemStride) * kTile, lane, w);
      load_pfB(pfB, srcB + (size_t)(e0 + (long)(j + 2) * elemStride) * kTile, rowbase, q);
    }
#pragma unroll
    for (int cm = 0; cm < 4; ++cm) { apa[cm] = npa[cm]; apb[cm] = npb[cm]; }
    if (j + 1 < nS) softBarrier();
  }

  float* pao = dstA + (size_t)blockIdx.x * kTile;
  float* pbo = dstB + (size_t)blockIdx.x * kTile;
#pragma unroll
  for (int cm = 0; cm < 4; ++cm) {
    *reinterpret_cast<f32x4*>(pao + rowbase + cm * 16 + q * 4) = apa[cm];
    *reinterpret_cast<f32x4*>(pbo + rowbase + cm * 16 + q * 4) = apb[cm];
  }
}

// ---------------- scan: apply nSteps elements, write states into out ----------------
__global__ __launch_bounds__(256, 4) void gdr_scan(
    const float* __restrict__ srcA, const float* __restrict__ srcB,
    const float* __restrict__ S0, float* __restrict__ out,
    int perChain, long chainBase, long idxBase, long elemStride,
    int nSteps, int tbMul, int tStep) {
  __shared__ unsigned short sAh[2][4096], sAl[2][4096];

  const int tid = threadIdx.x;
  const int lane = tid & 63, w = tid >> 6;
  const int q = lane >> 4, l15 = lane & 15;
  const int bh = blockIdx.x / perChain, id = blockIdx.x % perChain;
  const long e0 = (long)bh * chainBase + (long)id * idxBase;
  const int tBase = id * tbMul;
  const int rowbase = (w * 16 + l15) * 64;
  const int ad0 = (l15 + ((lane >> 4) & 1) * 32) * 4;
  const int ad1 = ad0 + 64;
  const bool lowh = lane < 32;

  f32x4 acc[4];
  {
    const float* Sb = (tBase == 0) ? (S0 + (size_t)bh * kTile)
                                   : (out + ((size_t)(tBase - 1) * kBH + bh) * kTile);
#pragma unroll
    for (int cm = 0; cm < 4; ++cm)
      acc[cm] = *reinterpret_cast<const f32x4*>(Sb + rowbase + cm * 16 + q * 4);
  }

  float pfA[16];
  f32x4 pfB[4];
  load_pfA(pfA, srcA + (size_t)e0 * kTile, lane, w);
  stage_A(sAh[0], sAl[0], pfA, lane, w);
  softBarrier();
  {
    const long e1 = e0 + (long)(nSteps > 1 ? 1 : 0) * elemStride;
    load_pfA(pfA, srcA + (size_t)e1 * kTile, lane, w);
    load_pfB(pfB, srcB + (size_t)e0 * kTile, rowbase, q);
  }

  for (int i = 0; i < nSteps; ++i) {
    const int cur = i & 1;
    f32x4 nacc[4];
#pragma unroll
    for (int cm = 0; cm < 4; ++cm) nacc[cm] = pfB[cm];
#pragma unroll
    for (int ks = 0; ks < 2; ++ks) {
      u32 p01h, p01l, p23h, p23l, q01h, q01l, q23h, q23l;
      pk_split(acc[2 * ks][0], acc[2 * ks][1], p01h, p01l);
      pk_split(acc[2 * ks][2], acc[2 * ks][3], p23h, p23l);
      pk_split(acc[2 * ks + 1][0], acc[2 * ks + 1][1], q01h, q01l);
      pk_split(acc[2 * ks + 1][2], acc[2 * ks + 1][3], q23h, q23l);
      const short8 bfh = gather_frag(p01h, p23h, q01h, q23h, ad0, ad1, lowh);
      const short8 bfl = gather_frag(p01l, p23l, q01l, q23l, ad0, ad1, lowh);
#pragma unroll
      for (int cm = 0; cm < 4; ++cm) {
        const int ai = swzi(cm * 16 + l15, ks * 32 + q * 8);
        const short8 ah = *reinterpret_cast<const short8*>(&sAh[cur][ai]);
        const short8 al = *reinterpret_cast<const short8*>(&sAl[cur][ai]);
        nacc[cm] = mfma16(ah, bfh, nacc[cm]);
        nacc[cm] = mfma16(ah, bfl, nacc[cm]);
        nacc[cm] = mfma16(al, bfh, nacc[cm]);
      }
    }
    if (i + 1 < nSteps) {
      stage_A(sAh[cur ^ 1], sAl[cur ^ 1], pfA, lane, w);  // element i+1
      const int ia = (i + 2 <= nSteps - 1) ? i + 2 : nSteps - 1;
      load_pfA(pfA, srcA + (size_t)(e0 + (long)ia * elemStride) * kTile, lane, w);
      load_pfB(pfB, srcB + (size_t)(e0 + (long)(i + 1) * elemStride) * kTile, rowbase, q);
    }
    // write state t
    const int t = tBase + (i + 1) * tStep - 1;
    float* o = out + ((size_t)t * kBH + bh) * kTile;
#pragma unroll
    for (int cm = 0; cm < 4; ++cm) {
      *reinterpret_cast<f32x4*>(o + rowbase + cm * 16 + q * 4) = nacc[cm];
      acc[cm] = nacc[cm];
    }
    if (i + 1 < nSteps) softBarrier();
  }
}

extern "C" void kernel_launch(void* const* d_in, const int* in_sizes, int n_in,
                              void* d_out, int out_size, void* d_ws, size_t ws_size,
                              hipStream_t stream) {
  const float* A  = (const float*)d_in[0];
  const float* Bm = (const float*)d_in[1];
  const float* S0 = (const float*)d_in[2];
  float* out = (float*)d_out;

  // workspace: PA[64*16], PB[64*16] tiles of 16 KB = 32 MB
  float* PA = (float*)d_ws;
  float* PB = PA + (size_t)kBH * kNC * kTile;

  // K1: chunk summaries. elements (ck*8+i)*64+bh, i=0..7
  gdr_fold<<<dim3(kBH * kNC), dim3(256), 0, stream>>>(
      A, Bm, PA, PB, kNC, 1L, (long)kCH * kBH, (long)kBH, kCH);
  // K2: scan 16 summaries (tiles bh*16+i); writes t = (i+1)*8-1 (7,15,...,127)
  gdr_scan<<<dim3(kBH), dim3(256), 0, stream>>>(
      PA, PB, S0, out, 1, (long)kNC, 0L, 1L, kNC, 0, kCH);
  // K3: in-chunk recurrence; elements (ck*8+i)*64+bh, start out[ck*8-1]/S0,
  //     writes t = ck*8+i for i=0..6
  gdr_scan<<<dim3(kBH * kNC), dim3(256), 0, stream>>>(
      A, Bm, S0, out, kNC, 1L, (long)kCH * kBH, (long)kBH, kCH - 1, kCH, 1);
}